// Round 2
// baseline (897.896 us; speedup 1.0000x reference)
//
#include <hip/hip_runtime.h>
#include <hip/hip_bf16.h>
#include <math.h>

// Dtypes per the reference (all jnp.float32): inputs and output are fp32 on
// device. Internal compute: bf16 MFMA with fp32 accumulation (threshold is
// 2% of absmax = 0.115 -> bf16 rounding is well within budget).
// x:(B,P,D) W1:(P,D,D)[d_out,e] b1:(P,D) W2:(P,D,D) b2:(P,D) gamma,beta:(D)
// out:(B,P,D).  B=2048 P=54 D=512.

#define B_DIM 2048
#define P_DIM 54
#define D_DIM 512

typedef __attribute__((ext_vector_type(8))) short short8;
typedef __attribute__((ext_vector_type(4))) float floatx4;

__device__ __forceinline__ unsigned short f2bf(float f) {
    union { float f; unsigned int i; } c; c.f = f;
    unsigned int r = c.i + 0x7FFFu + ((c.i >> 16) & 1u);  // RNE
    return (unsigned short)(r >> 16);
}

// two fp32 -> packed bf16x2 (RNE); lowers to v_cvt_pk_bf16_f32 on gfx950
__device__ __forceinline__ unsigned int f2bf2(float a, float b) {
    __hip_bfloat162 h2 = __float22bfloat162_rn(make_float2(a, b));
    unsigned int u; __builtin_memcpy(&u, &h2, 4); return u;
}

// 16B-per-lane async global->LDS (bf16 data only, used for the h tile).
__device__ __forceinline__ void gload_lds16(const unsigned short* g, unsigned short* l) {
    __builtin_amdgcn_global_load_lds((const __attribute__((address_space(1))) void*)g,
                                     (__attribute__((address_space(3))) void*)l,
                                     16, 0, 0);
}

// ---------------------------------------------------------------------------
// Kernel A: h = gelu_exact(x @ W1^T + b1) per patch, h stored bf16 in ws.
// 128x128 tile, BK=32. 256 threads = 4 waves; wave computes 64x64.
// fp32 global -> cvt bf16 -> LDS staging.
// ---------------------------------------------------------------------------
__global__ __launch_bounds__(256) void gemm1_gelu(
    const float* __restrict__ x,
    const float* __restrict__ W1,
    const float* __restrict__ b1,
    unsigned short* __restrict__ h)
{
    __shared__ __align__(16) unsigned short sA[128 * 32];
    __shared__ __align__(16) unsigned short sB[128 * 32];

    const int tid   = threadIdx.x;
    const int wave  = tid >> 6;
    const int lane  = tid & 63;
    const int quad  = lane >> 4;
    const int colid = lane & 15;

    const int m0 = blockIdx.x * 128;
    const int n0 = blockIdx.y * 128;
    const int p  = blockIdx.z;

    const long xstride = (long)P_DIM * D_DIM;  // row stride of x/h in elements
    const float* xp  = x  + (long)m0 * xstride + (long)p * D_DIM;
    const float* w1p = W1 + ((long)p * D_DIM + n0) * D_DIM;

    // staging map: thread -> (row = q*32 + tid>>3, 4 consecutive elems at (tid&7)*4)
    const int srow = tid >> 3;
    const int sch  = (tid & 7) * 4;

    floatx4 acc[4][4];
#pragma unroll
    for (int i = 0; i < 4; i++)
#pragma unroll
        for (int j = 0; j < 4; j++)
            acc[i][j] = (floatx4){0.f, 0.f, 0.f, 0.f};

    const int wm = (wave & 1) * 64;
    const int wn = (wave >> 1) * 64;

    for (int kt = 0; kt < D_DIM; kt += 32) {
        // load fp32 tiles to registers first (overlap with previous compute)
        float4 va[4], vb[4];
#pragma unroll
        for (int q = 0; q < 4; q++) {
            const int r = q * 32 + srow;
            va[q] = *(const float4*)(xp  + (long)r * xstride + kt + sch);
            vb[q] = *(const float4*)(w1p + (long)r * D_DIM   + kt + sch);
        }
        __syncthreads();
#pragma unroll
        for (int q = 0; q < 4; q++) {
            const int r = q * 32 + srow;
            uint2 pa, pb;
            pa.x = f2bf2(va[q].x, va[q].y); pa.y = f2bf2(va[q].z, va[q].w);
            pb.x = f2bf2(vb[q].x, vb[q].y); pb.y = f2bf2(vb[q].z, vb[q].w);
            *(uint2*)&sA[r * 32 + sch] = pa;
            *(uint2*)&sB[r * 32 + sch] = pb;
        }
        __syncthreads();

        short8 a[4], b[4];
#pragma unroll
        for (int i = 0; i < 4; i++) {
            a[i] = *(const short8*)&sA[(wm + i * 16 + colid) * 32 + quad * 8];
            b[i] = *(const short8*)&sB[(wn + i * 16 + colid) * 32 + quad * 8];
        }
#pragma unroll
        for (int i = 0; i < 4; i++)
#pragma unroll
            for (int j = 0; j < 4; j++)
                acc[i][j] = __builtin_amdgcn_mfma_f32_16x16x32_bf16(a[i], b[j], acc[i][j], 0, 0, 0);
    }

    // epilogue: +b1, exact-erf GELU, store bf16 h
#pragma unroll
    for (int j = 0; j < 4; j++) {
        const int n = n0 + wn + j * 16 + colid;
        const float bias = b1[p * D_DIM + n];
#pragma unroll
        for (int i = 0; i < 4; i++) {
#pragma unroll
            for (int r = 0; r < 4; r++) {
                const int m = m0 + wm + i * 16 + quad * 4 + r;
                float v = acc[i][j][r] + bias;
                v = 0.5f * v * (1.0f + erff(v * 0.70710678118654752f));
                h[(long)m * xstride + (long)p * D_DIM + n] = f2bf(v);
            }
        }
    }
}

// ---------------------------------------------------------------------------
// Kernel B: o = h @ W2^T + b2 + x, then LayerNorm over D. 64 rows x 512 cols
// per WG (full rows -> LN in-block). 512 threads = 8 waves; wave w owns cols
// [w*64, w*64+64). W2 staged fp32->bf16; h (already bf16) via global_load_lds.
// ---------------------------------------------------------------------------
__global__ __launch_bounds__(512) void gemm2_ln(
    const unsigned short* __restrict__ h,
    const float* __restrict__ W2,
    const float* __restrict__ b2,
    const float* __restrict__ x,
    const float* __restrict__ gamma,
    const float* __restrict__ beta,
    float* __restrict__ out)
{
    __shared__ __align__(16) unsigned short sH[64 * 32];
    __shared__ __align__(16) unsigned short sW[512 * 32];
    __shared__ float red1[64 * 8];
    __shared__ float red2[64 * 8];
    __shared__ float sMu[64], sRs[64];
    __shared__ float sG[512], sBt[512];

    const int tid   = threadIdx.x;
    const int wave  = tid >> 6;
    const int lane  = tid & 63;
    const int quad  = lane >> 4;
    const int colid = lane & 15;

    const int m0 = blockIdx.x * 64;
    const int p  = blockIdx.y;

    sG[tid]  = gamma[tid];
    sBt[tid] = beta[tid];

    const long rstride = (long)P_DIM * D_DIM;
    const unsigned short* hp = h + (long)m0 * rstride + (long)p * D_DIM;
    const float*         w2p = W2 + (long)p * D_DIM * D_DIM;

    const int srow = tid >> 3;        // 0..63 (W2 staging row within group)
    const int sch  = (tid & 7) * 4;
    const int hrow = lane >> 2;       // gload_lds16 lane map
    const int hoff = (lane & 3) * 8;

    floatx4 acc[4][4];
#pragma unroll
    for (int i = 0; i < 4; i++)
#pragma unroll
        for (int j = 0; j < 4; j++)
            acc[i][j] = (floatx4){0.f, 0.f, 0.f, 0.f};

    const int wn = wave * 64;

    for (int kt = 0; kt < D_DIM; kt += 32) {
        float4 vw[8];
#pragma unroll
        for (int q = 0; q < 8; q++) {
            const int r = q * 64 + srow;
            vw[q] = *(const float4*)(w2p + (long)r * D_DIM + kt + sch);
        }
        __syncthreads();
#pragma unroll
        for (int q = 0; q < 8; q++) {
            const int r = q * 64 + srow;
            uint2 pw;
            pw.x = f2bf2(vw[q].x, vw[q].y); pw.y = f2bf2(vw[q].z, vw[q].w);
            *(uint2*)&sW[r * 32 + sch] = pw;
        }
        if (wave < 4) {
            const int r = wave * 16;  // wave-uniform LDS base
            gload_lds16(hp + (long)(r + hrow) * rstride + kt + hoff, &sH[r * 32]);
        }
        __syncthreads();

        short8 a[4], b[4];
#pragma unroll
        for (int i = 0; i < 4; i++) {
            a[i] = *(const short8*)&sH[(i * 16 + colid) * 32 + quad * 8];
            b[i] = *(const short8*)&sW[(wn + i * 16 + colid) * 32 + quad * 8];
        }
#pragma unroll
        for (int i = 0; i < 4; i++)
#pragma unroll
            for (int j = 0; j < 4; j++)
                acc[i][j] = __builtin_amdgcn_mfma_f32_16x16x32_bf16(a[i], b[j], acc[i][j], 0, 0, 0);
    }

    // epilogue: +b2 + residual (fp32 x)
    const float* xp = x + (long)m0 * rstride + (long)p * D_DIM;
#pragma unroll
    for (int j = 0; j < 4; j++) {
        const int n = wn + j * 16 + colid;
        const float bias = b2[p * D_DIM + n];
#pragma unroll
        for (int i = 0; i < 4; i++) {
#pragma unroll
            for (int r = 0; r < 4; r++) {
                const int row = i * 16 + quad * 4 + r;
                acc[i][j][r] += bias + xp[(long)row * rstride + n];
            }
        }
    }

    // row-wise sum/sumsq: 16-lane butterfly within quad, then cross-wave LDS.
#pragma unroll
    for (int i = 0; i < 4; i++) {
#pragma unroll
        for (int r = 0; r < 4; r++) {
            float s1 = 0.f, s2 = 0.f;
#pragma unroll
            for (int j = 0; j < 4; j++) {
                const float v = acc[i][j][r];
                s1 += v; s2 += v * v;
            }
#pragma unroll
            for (int off = 1; off < 16; off <<= 1) {
                s1 += __shfl_xor(s1, off, 16);
                s2 += __shfl_xor(s2, off, 16);
            }
            if (colid == 0) {
                const int row = i * 16 + quad * 4 + r;
                red1[row * 8 + wave] = s1;
                red2[row * 8 + wave] = s2;
            }
        }
    }
    __syncthreads();
    if (tid < 64) {
        float s1 = 0.f, s2 = 0.f;
#pragma unroll
        for (int w = 0; w < 8; w++) { s1 += red1[tid * 8 + w]; s2 += red2[tid * 8 + w]; }
        const float mu  = s1 * (1.0f / (float)D_DIM);
        const float var = s2 * (1.0f / (float)D_DIM) - mu * mu;
        sMu[tid] = mu;
        sRs[tid] = rsqrtf(var + 1e-5f);
    }
    __syncthreads();

    float* op = out + (long)m0 * rstride + (long)p * D_DIM;
#pragma unroll
    for (int j = 0; j < 4; j++) {
        const int n = wn + j * 16 + colid;
        const float g = sG[n], bt = sBt[n];
#pragma unroll
        for (int i = 0; i < 4; i++) {
#pragma unroll
            for (int r = 0; r < 4; r++) {
                const int row = i * 16 + quad * 4 + r;
                const float v = (acc[i][j][r] - sMu[row]) * sRs[row] * g + bt;
                op[(long)row * rstride + n] = v;
            }
        }
    }
}

extern "C" void kernel_launch(void* const* d_in, const int* in_sizes, int n_in,
                              void* d_out, int out_size, void* d_ws, size_t ws_size,
                              hipStream_t stream) {
    const float* x     = (const float*)d_in[0];
    const float* W1    = (const float*)d_in[1];
    const float* b1    = (const float*)d_in[2];
    const float* W2    = (const float*)d_in[3];
    const float* b2    = (const float*)d_in[4];
    const float* gamma = (const float*)d_in[5];
    const float* beta  = (const float*)d_in[6];
    float* out = (float*)d_out;
    unsigned short* h = (unsigned short*)d_ws;  // B*P*D bf16 = 113 MB scratch

    dim3 gridA(B_DIM / 128, D_DIM / 128, P_DIM);
    gemm1_gelu<<<gridA, 256, 0, stream>>>(x, W1, b1, h);

    dim3 gridB(B_DIM / 64, P_DIM);
    gemm2_ln<<<gridB, 512, 0, stream>>>(h, W2, b2, x, gamma, beta, out);
}